// Round 5
// baseline (433.574 us; speedup 1.0000x reference)
//
#include <hip/hip_runtime.h>
#include <math.h>

constexpr int B = 32;
constexpr int NN = 2048;   // nodes
constexpr int E = 65536;   // edges
constexpr float SLOPE = 0.01f;

typedef __attribute__((ext_vector_type(8))) short bf16x8;
typedef __attribute__((ext_vector_type(4))) float f32x4;

__device__ __forceinline__ float lrelu(float x) { return x > 0.f ? x : SLOPE * x; }

__device__ __forceinline__ unsigned int pack_bf16(float lo, float hi) {
    unsigned int a = __float_as_uint(lo);
    unsigned int b = __float_as_uint(hi);
    a += 0x7fffu + ((a >> 16) & 1u);
    b += 0x7fffu + ((b >> 16) & 1u);
    return (a >> 16) | (b & 0xffff0000u);
}

__device__ __forceinline__ void unpack_bf16(unsigned int u, float& lo, float& hi) {
    lo = __uint_as_float(u << 16);
    hi = __uint_as_float(u & 0xffff0000u);
}

// ---------------- prep (blocks 8..11) + CSR-counter zero (blocks 0..7) ----------------
__global__ __launch_bounds__(256) void prep_zero_kernel(
    const float* __restrict__ W1c, const float* __restrict__ W2c,
    const float* __restrict__ W1v, const float* __restrict__ W2v,
    const float* __restrict__ W1e, const float* __restrict__ W2e,
    const float* __restrict__ W1o,
    float* __restrict__ W1cT, float* __restrict__ W2cT,
    float* __restrict__ W1vT, float* __restrict__ W2vT,
    float* __restrict__ W1sT, float* __restrict__ W1dT,
    unsigned short* __restrict__ W2eb, float* __restrict__ W1oT,
    int* __restrict__ cnt, int* __restrict__ cursor)
{
    int blk = blockIdx.x;
    if (blk < 8) {
        int i = blk * 256 + threadIdx.x;           // 0..2047
        cnt[i] = 0;
        cursor[i] = 0;
        return;
    }
    int t = (blk - 8) * 256 + threadIdx.x;         // 0..1023
    for (int i = t; i < 32 * 24; i += 1024) W1cT[(i % 24) * 32 + i / 24] = W1c[i];
    for (int i = t; i < 32 * 32; i += 1024) W2cT[(i % 32) * 32 + i / 32] = W2c[i];
    for (int i = t; i < 32 * 64; i += 1024) W1vT[(i % 64) * 32 + i / 64] = W1v[i];
    for (int i = t; i < 32 * 32; i += 1024) W2vT[(i % 32) * 32 + i / 32] = W2v[i];
    for (int i = t; i < 32 * 68; i += 1024) {
        int o = i / 68, j = i % 68;
        if (j < 34) W1sT[j * 32 + o] = W1e[i];
        else        W1dT[(j - 34) * 32 + o] = W1e[i];
    }
    for (int i = t; i < 32 * 32; i += 1024) {       // W2e row-major f32 -> bf16 (RNE)
        unsigned int u = __float_as_uint(W2e[i]);
        u += 0x7fffu + ((u >> 16) & 1u);
        W2eb[i] = (unsigned short)(u >> 16);
    }
    for (int i = t; i < 32 * 32; i += 1024) W1oT[(i % 32) * 32 + i / 32] = W1o[i];
}

// ---------------- CSR build ----------------
__global__ __launch_bounds__(256) void count_kernel(const int* __restrict__ edges, int* __restrict__ cnt)
{
    int e = blockIdx.x * 256 + threadIdx.x;
    if (e < E) atomicAdd(&cnt[edges[E + e]], 1);
}

__global__ __launch_bounds__(1024) void scan_kernel(const int* __restrict__ cnt, int* __restrict__ offs)
{
    __shared__ int s[1024];
    int t = threadIdx.x;
    int c0 = cnt[2 * t], c1 = cnt[2 * t + 1];
    int own = c0 + c1;
    s[t] = own;
    __syncthreads();
    int v = own;
    for (int d = 1; d < 1024; d <<= 1) {
        int add = (t >= d) ? s[t - d] : 0;
        __syncthreads();
        v += add;
        s[t] = v;
        __syncthreads();
    }
    int excl = v - own;
    offs[2 * t] = excl;
    offs[2 * t + 1] = excl + c0;
    if (t == 1023) offs[2048] = v;       // total = E
}

__global__ __launch_bounds__(256) void fill_kernel(
    const int* __restrict__ edges, const int* __restrict__ offs,
    int* __restrict__ cursor, int* __restrict__ elist)
{
    int e = blockIdx.x * 256 + threadIdx.x;
    if (e < E) {
        int d = edges[E + e];
        int p = atomicAdd(&cursor[d], 1);
        elist[offs[d] + p] = edges[e];
    }
}

// ---------------- vertex MLP: 2 threads per node (adjacent lanes), halved o-dim ----------------
__global__ __launch_bounds__(256) void vertex_kernel(
    const float* __restrict__ vert,
    const float* __restrict__ Wx,  const float* __restrict__ bx,
    const float* __restrict__ Wy,  const float* __restrict__ by,
    const float* __restrict__ Wth, const float* __restrict__ bth,
    const float* __restrict__ b1c, const float* __restrict__ b2c,
    const float* __restrict__ b1v, const float* __restrict__ b2v,
    const float* __restrict__ b1e,
    const float* __restrict__ W1cT, const float* __restrict__ W2cT,
    const float* __restrict__ W1vT, const float* __restrict__ W2vT,
    const float* __restrict__ W1sT, const float* __restrict__ W1dT,
    unsigned int* __restrict__ asrc, unsigned int* __restrict__ adst)
{
    int idx2 = blockIdx.x * 256 + threadIdx.x;     // 2*B*NN threads
    int node = idx2 >> 1;
    int p = idx2 & 1;
    int o0 = p << 4;                               // this thread owns outputs o0..o0+15
    const float* v = vert + (size_t)node * 11;
    float qk0 = v[0], qk1 = v[1], qk2 = v[2];
    float q00 = v[3], q01 = v[4], q02 = v[5];
    float qg0 = v[6], qg1 = v[7], qg2 = v[8];
    float col0 = v[9], col1 = v[10];

    float cf[64];                                  // full concat feature (assembled via shfl)
    #pragma unroll
    for (int half = 0; half < 2; ++half) {
        float a0 = half ? qg0 : q00;
        float a1 = half ? qg1 : q01;
        float a2 = half ? qg2 : q02;
        float c[24];                               // duplicated across the pair (cheap)
        #pragma unroll
        for (int k = 0; k < 8; ++k) {
            c[k]      = lrelu(qk0 * Wx[2 * k]  + a0 * Wx[2 * k + 1]  + bx[k]);
            c[8 + k]  = lrelu(qk1 * Wy[2 * k]  + a1 * Wy[2 * k + 1]  + by[k]);
            c[16 + k] = lrelu(qk2 * Wth[2 * k] + a2 * Wth[2 * k + 1] + bth[k]);
        }
        float h[16];
        #pragma unroll
        for (int o = 0; o < 16; ++o) h[o] = b1c[o0 + o];
        #pragma unroll
        for (int j = 0; j < 24; ++j) {
            float x = c[j];
            #pragma unroll
            for (int o = 0; o < 16; ++o) h[o] += x * W1cT[j * 32 + o0 + o];
        }
        float hf[32];
        #pragma unroll
        for (int i = 0; i < 16; ++i) {
            float t = lrelu(h[i]);
            hf[o0 + i] = t;
            hf[(o0 ^ 16) + i] = __shfl_xor(t, 1);
        }
        float g[16];
        #pragma unroll
        for (int o = 0; o < 16; ++o) g[o] = b2c[o0 + o];
        #pragma unroll
        for (int j = 0; j < 32; ++j) {
            float x = hf[j];
            #pragma unroll
            for (int o = 0; o < 16; ++o) g[o] += x * W2cT[j * 32 + o0 + o];
        }
        #pragma unroll
        for (int i = 0; i < 16; ++i) {
            float t = lrelu(g[i]);
            cf[half * 32 + o0 + i] = t;
            cf[half * 32 + (o0 ^ 16) + i] = __shfl_xor(t, 1);
        }
    }

    float v1[16];
    #pragma unroll
    for (int o = 0; o < 16; ++o) v1[o] = b1v[o0 + o];
    #pragma unroll
    for (int j = 0; j < 64; ++j) {
        float x = cf[j];
        #pragma unroll
        for (int o = 0; o < 16; ++o) v1[o] += x * W1vT[j * 32 + o0 + o];
    }
    float v1f[32];
    #pragma unroll
    for (int i = 0; i < 16; ++i) {
        float t = lrelu(v1[i]);
        v1f[o0 + i] = t;
        v1f[(o0 ^ 16) + i] = __shfl_xor(t, 1);
    }

    float v2[16];
    #pragma unroll
    for (int o = 0; o < 16; ++o) v2[o] = b2v[o0 + o];
    #pragma unroll
    for (int j = 0; j < 32; ++j) {
        float x = v1f[j];
        #pragma unroll
        for (int o = 0; o < 16; ++o) v2[o] += x * W2vT[j * 32 + o0 + o];
    }

    float vfrf[34];
    #pragma unroll
    for (int i = 0; i < 16; ++i) {
        float t = lrelu(v2[i]);
        vfrf[o0 + i] = t;
        vfrf[(o0 ^ 16) + i] = __shfl_xor(t, 1);
    }
    vfrf[32] = col0;
    vfrf[33] = col1;

    float as[16], ad[16];
    #pragma unroll
    for (int o = 0; o < 16; ++o) { as[o] = 0.f; ad[o] = b1e[o0 + o]; }
    #pragma unroll
    for (int j = 0; j < 34; ++j) {
        float x = vfrf[j];
        #pragma unroll
        for (int o = 0; o < 16; ++o) {
            as[o] += x * W1sT[j * 32 + o0 + o];
            ad[o] += x * W1dT[j * 32 + o0 + o];
        }
    }

    unsigned int* ps = asrc + ((size_t)node << 4) + (p << 3);   // 8 uints = 16 bf16
    unsigned int* pd = adst + ((size_t)node << 4) + (p << 3);
    #pragma unroll
    for (int q = 0; q < 8; ++q) {
        ps[q] = pack_bf16(as[2 * q], as[2 * q + 1]);
        pd[q] = pack_bf16(ad[2 * q], ad[2 * q + 1]);
    }
}

// ---------------- edge phase: MFMA chunks, per-dst waves, XCD-swizzled blocks,
//                  fused mean + node output MLP ----------------
__global__ __launch_bounds__(256, 6) void edge_kernel(
    const unsigned int* __restrict__ asrc, const unsigned int* __restrict__ adst,
    const int* __restrict__ elist, const int* __restrict__ offs,
    const unsigned short* __restrict__ W2eb, const float* __restrict__ b2e,
    const float* __restrict__ W1oT, const float* __restrict__ b1o,
    const float* __restrict__ W2o,  const float* __restrict__ b2o,
    float* __restrict__ fv)
{
    constexpr int DPW = 8;                          // dsts per wave
    // XCD-aware swizzle: phys blocks round-robin across 8 XCDs; remap so each
    // XCD owns 256 logical blocks = 4 consecutive batches (1 MB L2 working set).
    int logical = (blockIdx.x & 7) * 256 + (blockIdx.x >> 3);
    int lane = threadIdx.x & 63;
    int gw = logical * 4 + (threadIdx.x >> 6);      // 8192 waves total
    int b = gw >> 8;                                // 256 waves per batch
    int d0 = (gw & 255) * DPW;
    int col = lane & 15;
    int grp = lane >> 4;

    union U8 { unsigned int u[4]; bf16x8 v; uint4 q; };
    U8 Bf0, Bf1;
    Bf0.q = *(const uint4*)(W2eb + col * 32 + grp * 8);
    Bf1.q = *(const uint4*)(W2eb + (col + 16) * 32 + grp * 8);
    float bias0 = b2e[col];
    float bias1 = b2e[col + 16];
    float w2oc = W2o[lane & 31];
    float b1oc = b1o[lane & 31];

    for (int dd = 0; dd < DPW; ++dd) {
        int d = d0 + dd;
        int start = offs[d];
        int end = offs[d + 1];
        int deg = end - start;

        const uint4 du = *(const uint4*)(adst + (((size_t)(b * NN + d)) << 4) + grp * 4);
        float adr[8];
        unpack_bf16(du.x, adr[0], adr[1]);
        unpack_bf16(du.y, adr[2], adr[3]);
        unpack_bf16(du.z, adr[4], adr[5]);
        unpack_bf16(du.w, adr[6], adr[7]);

        float s0 = 0.f, s1 = 0.f;
        for (int e0 = start; e0 < end; e0 += 16) {
            int e = e0 + col;
            int ec = e < end ? e : end - 1;
            int src = elist[ec];
            const uint4 su = *(const uint4*)(asrc + (((size_t)(b * NN + src)) << 4) + grp * 4);
            float h[8];
            {
                float lo, hi;
                unpack_bf16(su.x, lo, hi);
                h[0] = fmaxf(lo + adr[0], 0.f); h[1] = fmaxf(hi + adr[1], 0.f);
                unpack_bf16(su.y, lo, hi);
                h[2] = fmaxf(lo + adr[2], 0.f); h[3] = fmaxf(hi + adr[3], 0.f);
                unpack_bf16(su.z, lo, hi);
                h[4] = fmaxf(lo + adr[4], 0.f); h[5] = fmaxf(hi + adr[5], 0.f);
                unpack_bf16(su.w, lo, hi);
                h[6] = fmaxf(lo + adr[6], 0.f); h[7] = fmaxf(hi + adr[7], 0.f);
            }
            U8 A;
            A.u[0] = pack_bf16(h[0], h[1]);
            A.u[1] = pack_bf16(h[2], h[3]);
            A.u[2] = pack_bf16(h[4], h[5]);
            A.u[3] = pack_bf16(h[6], h[7]);

            f32x4 acc0 = {bias0, bias0, bias0, bias0};
            f32x4 acc1 = {bias1, bias1, bias1, bias1};
            acc0 = __builtin_amdgcn_mfma_f32_16x16x32_bf16(A.v, Bf0.v, acc0, 0, 0, 0);
            acc1 = __builtin_amdgcn_mfma_f32_16x16x32_bf16(A.v, Bf1.v, acc1, 0, 0, 0);

            int rowbase = e0 + grp * 4;
            #pragma unroll
            for (int r = 0; r < 4; ++r) {
                bool valid = (rowbase + r) < end;
                s0 += valid ? lrelu(acc0[r]) : 0.f;
                s1 += valid ? lrelu(acc1[r]) : 0.f;
            }
        }

        s0 += __shfl_xor(s0, 16); s0 += __shfl_xor(s0, 32);
        s1 += __shfl_xor(s1, 16); s1 += __shfl_xor(s1, 32);

        float inv = 1.f / fmaxf((float)deg, 1.f);
        float a0 = s0 * inv;
        float a1 = s1 * inv;
        int o = lane & 31;
        float f1 = b1oc;
        #pragma unroll
        for (int j = 0; j < 16; ++j) {
            float aj = __shfl(a0, j);
            f1 += aj * W1oT[j * 32 + o];
            float ak = __shfl(a1, j);
            f1 += ak * W1oT[(16 + j) * 32 + o];
        }
        float t = fmaxf(f1, 0.f) * w2oc;
        t += __shfl_xor(t, 1);
        t += __shfl_xor(t, 2);
        t += __shfl_xor(t, 4);
        t += __shfl_xor(t, 8);
        t += __shfl_xor(t, 16);
        if (lane == 0) fv[(size_t)b * NN + d] = lrelu(t + b2o[0]);
    }
}

// ---------------- final: out[b] = sigmoid(dot(fv[b,:], Wg) + bg) ----------------
__global__ __launch_bounds__(256) void final_kernel(
    const float* __restrict__ fv, const float* __restrict__ Wg,
    const float* __restrict__ bg, float* __restrict__ out)
{
    int b = blockIdx.x;
    int t = threadIdx.x;
    float p = 0.f;
    for (int n = t; n < NN; n += 256) p += fv[(size_t)b * NN + n] * Wg[n];
    __shared__ float red[256];
    red[t] = p;
    __syncthreads();
    for (int s = 128; s > 0; s >>= 1) {
        if (t < s) red[t] += red[t + s];
        __syncthreads();
    }
    if (t == 0) {
        float x = red[0] + bg[0];
        out[b] = 1.f / (1.f + expf(-x));
    }
}

extern "C" void kernel_launch(void* const* d_in, const int* in_sizes, int n_in,
                              void* d_out, int out_size, void* d_ws, size_t ws_size,
                              hipStream_t stream)
{
    const float* vert = (const float*)d_in[0];
    const int*   edges = (const int*)d_in[1];
    const float* Wx  = (const float*)d_in[2];
    const float* bx  = (const float*)d_in[3];
    const float* Wy  = (const float*)d_in[4];
    const float* by  = (const float*)d_in[5];
    const float* Wth = (const float*)d_in[6];
    const float* bth = (const float*)d_in[7];
    const float* W1c = (const float*)d_in[8];
    const float* b1c = (const float*)d_in[9];
    const float* W2c = (const float*)d_in[10];
    const float* b2c = (const float*)d_in[11];
    const float* W1v = (const float*)d_in[12];
    const float* b1v = (const float*)d_in[13];
    const float* W2v = (const float*)d_in[14];
    const float* b2v = (const float*)d_in[15];
    const float* W1e = (const float*)d_in[16];
    const float* b1e = (const float*)d_in[17];
    const float* W2e = (const float*)d_in[18];
    const float* b2e = (const float*)d_in[19];
    const float* W1o = (const float*)d_in[20];
    const float* b1o = (const float*)d_in[21];
    const float* W2o = (const float*)d_in[22];
    const float* b2o = (const float*)d_in[23];
    const float* Wg  = (const float*)d_in[24];
    const float* bg  = (const float*)d_in[25];
    float* out = (float*)d_out;

    // workspace layout (~9 MB, all chunks 16B-aligned)
    char* w = (char*)d_ws;
    unsigned int* asrc = (unsigned int*)w; w += (size_t)B * NN * 32 * 2;  // bf16 pairs
    unsigned int* adst = (unsigned int*)w; w += (size_t)B * NN * 32 * 2;
    float* fv   = (float*)w; w += (size_t)B * NN * 4;
    float* W1cT = (float*)w; w += 32 * 24 * 4;
    float* W2cT = (float*)w; w += 32 * 32 * 4;
    float* W1vT = (float*)w; w += 32 * 64 * 4;
    float* W2vT = (float*)w; w += 32 * 32 * 4;
    float* W1sT = (float*)w; w += 34 * 32 * 4;
    float* W1dT = (float*)w; w += 34 * 32 * 4;
    float* W1oT = (float*)w; w += 32 * 32 * 4;
    unsigned short* W2eb = (unsigned short*)w; w += 32 * 32 * 2;
    int* cnt    = (int*)w;   w += NN * 4;
    int* cursor = (int*)w;   w += NN * 4;
    int* offs   = (int*)w;   w += 2052 * 4;          // NN+1 used, padded to 16B
    int* elist  = (int*)w;   w += E * 4;

    prep_zero_kernel<<<12, 256, 0, stream>>>(W1c, W2c, W1v, W2v, W1e, W2e, W1o,
                                             W1cT, W2cT, W1vT, W2vT, W1sT, W1dT,
                                             W2eb, W1oT, cnt, cursor);
    count_kernel<<<E / 256, 256, 0, stream>>>(edges, cnt);
    scan_kernel<<<1, 1024, 0, stream>>>(cnt, offs);
    fill_kernel<<<E / 256, 256, 0, stream>>>(edges, offs, cursor, elist);

    vertex_kernel<<<(2 * B * NN) / 256, 256, 0, stream>>>(
        vert, Wx, bx, Wy, by, Wth, bth, b1c, b2c, b1v, b2v, b1e,
        W1cT, W2cT, W1vT, W2vT, W1sT, W1dT, asrc, adst);

    edge_kernel<<<(B * NN / 8) / 4, 256, 0, stream>>>(
        asrc, adst, elist, offs, W2eb, b2e, W1oT, b1o, W2o, b2o, fv);

    final_kernel<<<B, 256, 0, stream>>>(fv, Wg, bg, out);
}

// Round 6
// 240.183 us; speedup vs baseline: 1.8052x; 1.8052x over previous
//
#include <hip/hip_runtime.h>
#include <math.h>

constexpr int B = 32;
constexpr int NN = 2048;   // nodes
constexpr int E = 65536;   // edges
constexpr float SLOPE = 0.01f;

typedef __attribute__((ext_vector_type(8))) short bf16x8;
typedef __attribute__((ext_vector_type(4))) float f32x4;

__device__ __forceinline__ float lrelu(float x) { return x > 0.f ? x : SLOPE * x; }

__device__ __forceinline__ unsigned int pack_bf16(float lo, float hi) {
    unsigned int a = __float_as_uint(lo);
    unsigned int b = __float_as_uint(hi);
    a += 0x7fffu + ((a >> 16) & 1u);
    b += 0x7fffu + ((b >> 16) & 1u);
    return (a >> 16) | (b & 0xffff0000u);
}

__device__ __forceinline__ void unpack_bf16(unsigned int u, float& lo, float& hi) {
    lo = __uint_as_float(u << 16);
    hi = __uint_as_float(u & 0xffff0000u);
}

// ---------------- prep (blocks 8..11) + CSR-counter zero (blocks 0..7) ----------------
__global__ __launch_bounds__(256) void prep_zero_kernel(
    const float* __restrict__ W1c, const float* __restrict__ W2c,
    const float* __restrict__ W1v, const float* __restrict__ W2v,
    const float* __restrict__ W1e, const float* __restrict__ W2e,
    const float* __restrict__ W1o,
    float* __restrict__ W1cT, float* __restrict__ W2cT,
    float* __restrict__ W1vT, float* __restrict__ W2vT,
    float* __restrict__ W1sT, float* __restrict__ W1dT,
    unsigned short* __restrict__ W2eb, float* __restrict__ W1oT,
    int* __restrict__ cnt, int* __restrict__ cursor)
{
    int blk = blockIdx.x;
    if (blk < 8) {
        int i = blk * 256 + threadIdx.x;           // 0..2047
        cnt[i] = 0;
        cursor[i] = 0;
        return;
    }
    int t = (blk - 8) * 256 + threadIdx.x;         // 0..1023
    for (int i = t; i < 32 * 24; i += 1024) W1cT[(i % 24) * 32 + i / 24] = W1c[i];
    for (int i = t; i < 32 * 32; i += 1024) W2cT[(i % 32) * 32 + i / 32] = W2c[i];
    for (int i = t; i < 32 * 64; i += 1024) W1vT[(i % 64) * 32 + i / 64] = W1v[i];
    for (int i = t; i < 32 * 32; i += 1024) W2vT[(i % 32) * 32 + i / 32] = W2v[i];
    for (int i = t; i < 32 * 68; i += 1024) {
        int o = i / 68, j = i % 68;
        if (j < 34) W1sT[j * 32 + o] = W1e[i];
        else        W1dT[(j - 34) * 32 + o] = W1e[i];
    }
    for (int i = t; i < 32 * 32; i += 1024) {       // W2e row-major f32 -> bf16 (RNE)
        unsigned int u = __float_as_uint(W2e[i]);
        u += 0x7fffu + ((u >> 16) & 1u);
        W2eb[i] = (unsigned short)(u >> 16);
    }
    for (int i = t; i < 32 * 32; i += 1024) W1oT[(i % 32) * 32 + i / 32] = W1o[i];
}

// ---------------- CSR build ----------------
__global__ __launch_bounds__(256) void count_kernel(const int* __restrict__ edges, int* __restrict__ cnt)
{
    int e = blockIdx.x * 256 + threadIdx.x;
    if (e < E) atomicAdd(&cnt[edges[E + e]], 1);
}

__global__ __launch_bounds__(1024) void scan_kernel(const int* __restrict__ cnt, int* __restrict__ offs)
{
    __shared__ int s[1024];
    int t = threadIdx.x;
    int c0 = cnt[2 * t], c1 = cnt[2 * t + 1];
    int own = c0 + c1;
    s[t] = own;
    __syncthreads();
    int v = own;
    for (int d = 1; d < 1024; d <<= 1) {
        int add = (t >= d) ? s[t - d] : 0;
        __syncthreads();
        v += add;
        s[t] = v;
        __syncthreads();
    }
    int excl = v - own;
    offs[2 * t] = excl;
    offs[2 * t + 1] = excl + c0;
    if (t == 1023) offs[2048] = v;       // total = E
}

__global__ __launch_bounds__(256) void fill_kernel(
    const int* __restrict__ edges, const int* __restrict__ offs,
    int* __restrict__ cursor, int* __restrict__ elist)
{
    int e = blockIdx.x * 256 + threadIdx.x;
    if (e < E) {
        int d = edges[E + e];
        int p = atomicAdd(&cursor[d], 1);
        elist[offs[d] + p] = edges[e];
    }
}

// ---------------- vertex MLP + per-node edge-layer-1 projections (bf16) ----------------
// 1 thread per node, all-static register arrays (rule #20: no runtime indexing).
__global__ __launch_bounds__(256) void vertex_kernel(
    const float* __restrict__ vert,
    const float* __restrict__ Wx,  const float* __restrict__ bx,
    const float* __restrict__ Wy,  const float* __restrict__ by,
    const float* __restrict__ Wth, const float* __restrict__ bth,
    const float* __restrict__ b1c, const float* __restrict__ b2c,
    const float* __restrict__ b1v, const float* __restrict__ b2v,
    const float* __restrict__ b1e,
    const float* __restrict__ W1cT, const float* __restrict__ W2cT,
    const float* __restrict__ W1vT, const float* __restrict__ W2vT,
    const float* __restrict__ W1sT, const float* __restrict__ W1dT,
    unsigned int* __restrict__ asrc, unsigned int* __restrict__ adst)
{
    int idx = blockIdx.x * 256 + threadIdx.x;
    if (idx >= B * NN) return;
    const float* v = vert + (size_t)idx * 11;
    float qk0 = v[0], qk1 = v[1], qk2 = v[2];
    float q00 = v[3], q01 = v[4], q02 = v[5];
    float qg0 = v[6], qg1 = v[7], qg2 = v[8];
    float col0 = v[9], col1 = v[10];

    float cf[64];
    #pragma unroll
    for (int half = 0; half < 2; ++half) {
        float a0 = half ? qg0 : q00;
        float a1 = half ? qg1 : q01;
        float a2 = half ? qg2 : q02;
        float c[24];
        #pragma unroll
        for (int k = 0; k < 8; ++k) {
            c[k]      = lrelu(qk0 * Wx[2 * k]  + a0 * Wx[2 * k + 1]  + bx[k]);
            c[8 + k]  = lrelu(qk1 * Wy[2 * k]  + a1 * Wy[2 * k + 1]  + by[k]);
            c[16 + k] = lrelu(qk2 * Wth[2 * k] + a2 * Wth[2 * k + 1] + bth[k]);
        }
        float h[32];
        #pragma unroll
        for (int o = 0; o < 32; ++o) h[o] = b1c[o];
        #pragma unroll
        for (int j = 0; j < 24; ++j) {
            float x = c[j];
            #pragma unroll
            for (int o = 0; o < 32; ++o) h[o] += x * W1cT[j * 32 + o];
        }
        #pragma unroll
        for (int o = 0; o < 32; ++o) h[o] = lrelu(h[o]);
        float g[32];
        #pragma unroll
        for (int o = 0; o < 32; ++o) g[o] = b2c[o];
        #pragma unroll
        for (int j = 0; j < 32; ++j) {
            float x = h[j];
            #pragma unroll
            for (int o = 0; o < 32; ++o) g[o] += x * W2cT[j * 32 + o];
        }
        #pragma unroll
        for (int o = 0; o < 32; ++o) cf[half * 32 + o] = lrelu(g[o]);
    }

    float v1[32];
    #pragma unroll
    for (int o = 0; o < 32; ++o) v1[o] = b1v[o];
    #pragma unroll
    for (int j = 0; j < 64; ++j) {
        float x = cf[j];
        #pragma unroll
        for (int o = 0; o < 32; ++o) v1[o] += x * W1vT[j * 32 + o];
    }
    #pragma unroll
    for (int o = 0; o < 32; ++o) v1[o] = lrelu(v1[o]);

    float v2[32];
    #pragma unroll
    for (int o = 0; o < 32; ++o) v2[o] = b2v[o];
    #pragma unroll
    for (int j = 0; j < 32; ++j) {
        float x = v1[j];
        #pragma unroll
        for (int o = 0; o < 32; ++o) v2[o] += x * W2vT[j * 32 + o];
    }

    float vfr[34];
    #pragma unroll
    for (int o = 0; o < 32; ++o) vfr[o] = lrelu(v2[o]);
    vfr[32] = col0;
    vfr[33] = col1;

    float as[32], ad[32];
    #pragma unroll
    for (int o = 0; o < 32; ++o) { as[o] = 0.f; ad[o] = b1e[o]; }
    #pragma unroll
    for (int j = 0; j < 34; ++j) {
        float x = vfr[j];
        #pragma unroll
        for (int o = 0; o < 32; ++o) {
            as[o] += x * W1sT[j * 32 + o];
            ad[o] += x * W1dT[j * 32 + o];
        }
    }

    unsigned int* ps = asrc + ((size_t)idx << 4);   // 16 uints = 32 bf16
    unsigned int* pd = adst + ((size_t)idx << 4);
    #pragma unroll
    for (int q = 0; q < 16; ++q) {
        ps[q] = pack_bf16(as[2 * q], as[2 * q + 1]);
        pd[q] = pack_bf16(ad[2 * q], ad[2 * q + 1]);
    }
}

// ---------------- edge phase: MFMA chunks, per-dst waves, XCD-swizzled blocks,
//                  fused mean + node output MLP ----------------
__global__ __launch_bounds__(256, 6) void edge_kernel(
    const unsigned int* __restrict__ asrc, const unsigned int* __restrict__ adst,
    const int* __restrict__ elist, const int* __restrict__ offs,
    const unsigned short* __restrict__ W2eb, const float* __restrict__ b2e,
    const float* __restrict__ W1oT, const float* __restrict__ b1o,
    const float* __restrict__ W2o,  const float* __restrict__ b2o,
    float* __restrict__ fv)
{
    constexpr int DPW = 8;                          // dsts per wave
    // XCD-aware swizzle: phys blocks round-robin across 8 XCDs; remap so each
    // XCD owns 256 logical blocks = 4 consecutive batches (1 MB L2 working set).
    int logical = (blockIdx.x & 7) * 256 + (blockIdx.x >> 3);
    int lane = threadIdx.x & 63;
    int gw = logical * 4 + (threadIdx.x >> 6);      // 8192 waves total
    int b = gw >> 8;                                // 256 waves per batch
    int d0 = (gw & 255) * DPW;
    int col = lane & 15;
    int grp = lane >> 4;

    union U8 { unsigned int u[4]; bf16x8 v; uint4 q; };
    U8 Bf0, Bf1;
    Bf0.q = *(const uint4*)(W2eb + col * 32 + grp * 8);
    Bf1.q = *(const uint4*)(W2eb + (col + 16) * 32 + grp * 8);
    float bias0 = b2e[col];
    float bias1 = b2e[col + 16];
    float w2oc = W2o[lane & 31];
    float b1oc = b1o[lane & 31];

    for (int dd = 0; dd < DPW; ++dd) {
        int d = d0 + dd;
        int start = offs[d];
        int end = offs[d + 1];
        int deg = end - start;

        const uint4 du = *(const uint4*)(adst + (((size_t)(b * NN + d)) << 4) + grp * 4);
        float adr[8];
        unpack_bf16(du.x, adr[0], adr[1]);
        unpack_bf16(du.y, adr[2], adr[3]);
        unpack_bf16(du.z, adr[4], adr[5]);
        unpack_bf16(du.w, adr[6], adr[7]);

        float s0 = 0.f, s1 = 0.f;
        for (int e0 = start; e0 < end; e0 += 16) {
            int e = e0 + col;
            int ec = e < end ? e : end - 1;
            int src = elist[ec];
            const uint4 su = *(const uint4*)(asrc + (((size_t)(b * NN + src)) << 4) + grp * 4);
            float h[8];
            {
                float lo, hi;
                unpack_bf16(su.x, lo, hi);
                h[0] = fmaxf(lo + adr[0], 0.f); h[1] = fmaxf(hi + adr[1], 0.f);
                unpack_bf16(su.y, lo, hi);
                h[2] = fmaxf(lo + adr[2], 0.f); h[3] = fmaxf(hi + adr[3], 0.f);
                unpack_bf16(su.z, lo, hi);
                h[4] = fmaxf(lo + adr[4], 0.f); h[5] = fmaxf(hi + adr[5], 0.f);
                unpack_bf16(su.w, lo, hi);
                h[6] = fmaxf(lo + adr[6], 0.f); h[7] = fmaxf(hi + adr[7], 0.f);
            }
            U8 A;
            A.u[0] = pack_bf16(h[0], h[1]);
            A.u[1] = pack_bf16(h[2], h[3]);
            A.u[2] = pack_bf16(h[4], h[5]);
            A.u[3] = pack_bf16(h[6], h[7]);

            f32x4 acc0 = {bias0, bias0, bias0, bias0};
            f32x4 acc1 = {bias1, bias1, bias1, bias1};
            acc0 = __builtin_amdgcn_mfma_f32_16x16x32_bf16(A.v, Bf0.v, acc0, 0, 0, 0);
            acc1 = __builtin_amdgcn_mfma_f32_16x16x32_bf16(A.v, Bf1.v, acc1, 0, 0, 0);

            int rowbase = e0 + grp * 4;
            #pragma unroll
            for (int r = 0; r < 4; ++r) {
                bool valid = (rowbase + r) < end;
                s0 += valid ? lrelu(acc0[r]) : 0.f;
                s1 += valid ? lrelu(acc1[r]) : 0.f;
            }
        }

        s0 += __shfl_xor(s0, 16); s0 += __shfl_xor(s0, 32);
        s1 += __shfl_xor(s1, 16); s1 += __shfl_xor(s1, 32);

        float inv = 1.f / fmaxf((float)deg, 1.f);
        float a0 = s0 * inv;
        float a1 = s1 * inv;
        int o = lane & 31;
        float f1 = b1oc;
        #pragma unroll
        for (int j = 0; j < 16; ++j) {
            float aj = __shfl(a0, j);
            f1 += aj * W1oT[j * 32 + o];
            float ak = __shfl(a1, j);
            f1 += ak * W1oT[(16 + j) * 32 + o];
        }
        float t = fmaxf(f1, 0.f) * w2oc;
        t += __shfl_xor(t, 1);
        t += __shfl_xor(t, 2);
        t += __shfl_xor(t, 4);
        t += __shfl_xor(t, 8);
        t += __shfl_xor(t, 16);
        if (lane == 0) fv[(size_t)b * NN + d] = lrelu(t + b2o[0]);
    }
}

// ---------------- final: out[b] = sigmoid(dot(fv[b,:], Wg) + bg) ----------------
__global__ __launch_bounds__(256) void final_kernel(
    const float* __restrict__ fv, const float* __restrict__ Wg,
    const float* __restrict__ bg, float* __restrict__ out)
{
    int b = blockIdx.x;
    int t = threadIdx.x;
    float p = 0.f;
    for (int n = t; n < NN; n += 256) p += fv[(size_t)b * NN + n] * Wg[n];
    __shared__ float red[256];
    red[t] = p;
    __syncthreads();
    for (int s = 128; s > 0; s >>= 1) {
        if (t < s) red[t] += red[t + s];
        __syncthreads();
    }
    if (t == 0) {
        float x = red[0] + bg[0];
        out[b] = 1.f / (1.f + expf(-x));
    }
}

extern "C" void kernel_launch(void* const* d_in, const int* in_sizes, int n_in,
                              void* d_out, int out_size, void* d_ws, size_t ws_size,
                              hipStream_t stream)
{
    const float* vert = (const float*)d_in[0];
    const int*   edges = (const int*)d_in[1];
    const float* Wx  = (const float*)d_in[2];
    const float* bx  = (const float*)d_in[3];
    const float* Wy  = (const float*)d_in[4];
    const float* by  = (const float*)d_in[5];
    const float* Wth = (const float*)d_in[6];
    const float* bth = (const float*)d_in[7];
    const float* W1c = (const float*)d_in[8];
    const float* b1c = (const float*)d_in[9];
    const float* W2c = (const float*)d_in[10];
    const float* b2c = (const float*)d_in[11];
    const float* W1v = (const float*)d_in[12];
    const float* b1v = (const float*)d_in[13];
    const float* W2v = (const float*)d_in[14];
    const float* b2v = (const float*)d_in[15];
    const float* W1e = (const float*)d_in[16];
    const float* b1e = (const float*)d_in[17];
    const float* W2e = (const float*)d_in[18];
    const float* b2e = (const float*)d_in[19];
    const float* W1o = (const float*)d_in[20];
    const float* b1o = (const float*)d_in[21];
    const float* W2o = (const float*)d_in[22];
    const float* b2o = (const float*)d_in[23];
    const float* Wg  = (const float*)d_in[24];
    const float* bg  = (const float*)d_in[25];
    float* out = (float*)d_out;

    // workspace layout (~9 MB, all chunks 16B-aligned)
    char* w = (char*)d_ws;
    unsigned int* asrc = (unsigned int*)w; w += (size_t)B * NN * 32 * 2;  // bf16 pairs
    unsigned int* adst = (unsigned int*)w; w += (size_t)B * NN * 32 * 2;
    float* fv   = (float*)w; w += (size_t)B * NN * 4;
    float* W1cT = (float*)w; w += 32 * 24 * 4;
    float* W2cT = (float*)w; w += 32 * 32 * 4;
    float* W1vT = (float*)w; w += 32 * 64 * 4;
    float* W2vT = (float*)w; w += 32 * 32 * 4;
    float* W1sT = (float*)w; w += 34 * 32 * 4;
    float* W1dT = (float*)w; w += 34 * 32 * 4;
    float* W1oT = (float*)w; w += 32 * 32 * 4;
    unsigned short* W2eb = (unsigned short*)w; w += 32 * 32 * 2;
    int* cnt    = (int*)w;   w += NN * 4;
    int* cursor = (int*)w;   w += NN * 4;
    int* offs   = (int*)w;   w += 2052 * 4;          // NN+1 used, padded to 16B
    int* elist  = (int*)w;   w += E * 4;

    prep_zero_kernel<<<12, 256, 0, stream>>>(W1c, W2c, W1v, W2v, W1e, W2e, W1o,
                                             W1cT, W2cT, W1vT, W2vT, W1sT, W1dT,
                                             W2eb, W1oT, cnt, cursor);
    count_kernel<<<E / 256, 256, 0, stream>>>(edges, cnt);
    scan_kernel<<<1, 1024, 0, stream>>>(cnt, offs);
    fill_kernel<<<E / 256, 256, 0, stream>>>(edges, offs, cursor, elist);

    vertex_kernel<<<(B * NN) / 256, 256, 0, stream>>>(
        vert, Wx, bx, Wy, by, Wth, bth, b1c, b2c, b1v, b2v, b1e,
        W1cT, W2cT, W1vT, W2vT, W1sT, W1dT, asrc, adst);

    edge_kernel<<<(B * NN / 8) / 4, 256, 0, stream>>>(
        asrc, adst, elist, offs, W2eb, b2e, W1oT, b1o, W2o, b2o, fv);

    final_kernel<<<B, 256, 0, stream>>>(fv, Wg, bg, out);
}